// Round 11
// baseline (44.666 us; speedup 1.0000x reference)
//
#include <hip/hip_runtime.h>
#include <hip/hip_bf16.h>
#include <math.h>

#define Bsz 8
#define Nn  2048
#define Ff  256
#define KCAP 512
#define THR 60.0f

typedef short short8 __attribute__((ext_vector_type(8)));
typedef float f32x4  __attribute__((ext_vector_type(4)));
typedef unsigned short u16x4 __attribute__((ext_vector_type(4)));
typedef unsigned short u16x8 __attribute__((ext_vector_type(8)));
typedef unsigned int uint;

static __device__ __forceinline__ unsigned short f2bf(float v) {
    __hip_bfloat16 b = __float2bfloat16(v);
    return *reinterpret_cast<unsigned short*>(&b);
}
static __device__ __forceinline__ float bf2f(unsigned short u) {
    return __uint_as_float((uint)u << 16);
}
static __device__ __forceinline__ float fast_rcp(float x) {
    return __builtin_amdgcn_rcpf(x);
}

// ============ k_h: h = X@W^T + b -> h (B,N,F) bf16 row-major ; s1 ; s2 ============
// 512 blocks x 256 thr; block = 32 n-rows; 2 blocks/CU co-resident (37 KB LDS).
__global__ __launch_bounds__(256) void k_h(const float* __restrict__ X,
                                           const float* __restrict__ W,
                                           const float* __restrict__ Wb,
                                           const float* __restrict__ a1,
                                           const float* __restrict__ a2,
                                           unsigned short* __restrict__ h,
                                           float* __restrict__ s1,
                                           float* __restrict__ s2) {
    __shared__ char smem[37888];
    char* w_lds = smem;                                 // [256 o][64 f] bf16, byte ^= (o&7)<<4 ; reused as h-tile
    char* x_lds = smem + 32768;                         // [32 n][64 f] bf16, byte ^= (n&7)<<4
    float (*sred1)[2][16] = (float(*)[2][16])(smem + 36864);
    float (*sred2)[2][16] = (float(*)[2][16])(smem + 36864 + 512);

    const int tid  = threadIdx.x;
    const int lane = tid & 63;
    const int w    = tid >> 6;
    const int r0   = blockIdx.x * 32;
    const int b    = r0 >> 11;
    const int n0   = r0 & 2047;

    f32x4 acc[4][2];
#pragma unroll
    for (int mt = 0; mt < 4; mt++)
#pragma unroll
        for (int nt = 0; nt < 2; nt++) acc[mt][nt] = (f32x4)0.f;

    for (int kc = 0; kc < 4; kc++) {
        const int f0 = kc * 64;
        __syncthreads();
#pragma unroll
        for (int p = 0; p < 16; p++) {
            int idx = tid + p * 256;
            int o = idx >> 4, fi = idx & 15;
            float4 v = *(const float4*)&W[(size_t)o * Ff + f0 + fi * 4];
            u16x4 pk = {f2bf(v.x), f2bf(v.y), f2bf(v.z), f2bf(v.w)};
            *(u16x4*)(w_lds + ((o * 128 + fi * 8) ^ ((o & 7) << 4))) = pk;
        }
#pragma unroll
        for (int p = 0; p < 2; p++) {
            int idx = tid + p * 256;
            int n = idx >> 4, fi = idx & 15;
            float4 v = *(const float4*)&X[(size_t)(r0 + n) * Ff + f0 + fi * 4];
            u16x4 pk = {f2bf(v.x), f2bf(v.y), f2bf(v.z), f2bf(v.w)};
            *(u16x4*)(x_lds + ((n * 128 + fi * 8) ^ ((n & 7) << 4))) = pk;
        }
        __syncthreads();
#pragma unroll
        for (int kt = 0; kt < 2; kt++) {
            short8 bfr[2];
#pragma unroll
            for (int nt = 0; nt < 2; nt++) {
                int n = nt * 16 + (lane & 15);
                bfr[nt] = *(const short8*)(x_lds + ((n * 128 + kt * 64 + (lane >> 4) * 16) ^ ((n & 7) << 4)));
            }
#pragma unroll
            for (int mt = 0; mt < 4; mt++) {
                int o = w * 64 + mt * 16 + (lane & 15);
                short8 afr = *(const short8*)(w_lds + ((o * 128 + kt * 64 + (lane >> 4) * 16) ^ ((o & 7) << 4)));
#pragma unroll
                for (int nt = 0; nt < 2; nt++)
                    acc[mt][nt] = __builtin_amdgcn_mfma_f32_16x16x32_bf16(afr, bfr[nt], acc[mt][nt], 0, 0, 0);
            }
        }
    }

    // epilogue: bias, s1/s2 partials, h tile -> LDS (row-major, swizzled)
    __syncthreads();    // MFMA reads of w_lds done; reuse as h tile [32 n][256 o] bf16
    float s1p[2] = {0.f, 0.f};
    float s2p[2] = {0.f, 0.f};
#pragma unroll
    for (int mt = 0; mt < 4; mt++) {
#pragma unroll
        for (int reg = 0; reg < 4; reg++) {
            int o = w * 64 + mt * 16 + (lane >> 4) * 4 + reg;
            float wb = Wb[o], a1v = a1[o], a2v = a2[o];
#pragma unroll
            for (int nt = 0; nt < 2; nt++) {
                float hv = acc[mt][nt][reg] + wb;
                int nl = nt * 16 + (lane & 15);
                *(unsigned short*)(w_lds + nl * 512 + ((o * 2) ^ ((nl & 7) << 4))) = f2bf(hv);
                s1p[nt] += hv * a1v;
                s2p[nt] += hv * a2v;
            }
        }
    }
#pragma unroll
    for (int nt = 0; nt < 2; nt++) {
        s1p[nt] += __shfl_xor(s1p[nt], 16); s1p[nt] += __shfl_xor(s1p[nt], 32);
        s2p[nt] += __shfl_xor(s2p[nt], 16); s2p[nt] += __shfl_xor(s2p[nt], 32);
    }
    if (lane < 16) {
#pragma unroll
        for (int nt = 0; nt < 2; nt++) { sred1[w][nt][lane] = s1p[nt]; sred2[w][nt][lane] = s2p[nt]; }
    }
    __syncthreads();

    // coalesced h store: 32 rows x 256 cols bf16 = 16 KB
#pragma unroll
    for (int p = 0; p < 4; p++) {
        int id = tid + p * 256;
        int nl = id >> 5;
        int c16 = (id & 31) * 16;
        u16x8 v = *(const u16x8*)(w_lds + nl * 512 + (c16 ^ ((nl & 7) << 4)));
        *(u16x8*)&h[((size_t)(b * Nn + n0 + nl)) * Ff + (id & 31) * 8] = v;
    }
    if (tid < 32) {
        int nt = tid >> 4, col = tid & 15;
        s1[b * Nn + n0 + nt * 16 + col] = sred1[0][nt][col] + sred1[1][nt][col] + sred1[2][nt][col] + sred1[3][nt][col];
    } else if (tid < 64) {
        int t2 = tid - 32;
        int nt = t2 >> 4, col = t2 & 15;
        s2[b * Nn + n0 + nt * 16 + col] = sred2[0][nt][col] + sred2[1][nt][col] + sred2[2][nt][col] + sred2[3][nt][col];
    }
}

// ============ k_attn: fused shortlist + sparse gather-softmax, 2 rows/block ============
// 1024 blocks x 512 thr; block = rows {i0, i0+1}. Sub-row r = tid>>8 (wave-aligned),
// 256 thr/row, 8 j/thread (2 float4 per array in flight).
// phase 2: wave w = batch b; loops both rows; lane owns 4 f-cols.
__global__ __launch_bounds__(512) void k_attn(const unsigned short* __restrict__ h,
                                              const float* __restrict__ s1,
                                              const float* __restrict__ s2,
                                              const float* __restrict__ Ageo,
                                              const float* __restrict__ Dm,
                                              const float* __restrict__ ab_p,
                                              const float* __restrict__ thr_p,
                                              float* __restrict__ out) {
    __shared__ uint  ejs[2][KCAP];
    __shared__ float emks[2][KCAP];
    __shared__ float edgs[2][KCAP];
    __shared__ float red[8];
    __shared__ uint  cptr[2];

    const int i0   = blockIdx.x * 2;
    const int tid  = threadIdx.x;
    const int lane = tid & 63;
    const int w    = tid >> 6;       // 0..7
    const int r    = tid >> 8;       // sub-row 0/1 (waves 0-3 -> row 0, 4-7 -> row 1)
    const int i    = i0 + r;
    const float c10 = 10.0f * thr_p[0];

    // ---- phase 1: shortlist for rows i0, i0+1 ----
    if (tid < 2) cptr[tid] = 0;
    const int j0 = (tid & 255) * 8;
    float4 a0 = *(const float4*)&Ageo[(size_t)i * Nn + j0];
    float4 a1v4 = *(const float4*)&Ageo[(size_t)i * Nn + j0 + 4];
    float4 d0 = *(const float4*)&Dm[(size_t)i * Nn + j0];
    float4 d1 = *(const float4*)&Dm[(size_t)i * Nn + j0 + 4];
    float av[8] = {a0.x, a0.y, a0.z, a0.w, a1v4.x, a1v4.y, a1v4.z, a1v4.w};
    float dv[8] = {d0.x, d0.y, d0.z, d0.w, d1.x, d1.y, d1.z, d1.w};
    float mk[8], gg[8];
    float m = 0.0f;
#pragma unroll
    for (int c = 0; c < 8; c++) {
        float dd = (j0 + c == i) ? 1.0f : dv[c];
        float mkv = fast_rcp(1.0f + __expf(c10 - 10.0f * av[c]));
        float g   = mkv * fast_rcp(dd + 1e-5f);
        mk[c] = mkv;
        gg[c] = g;
        m = fmaxf(m, g);
    }
#pragma unroll
    for (int dd = 32; dd; dd >>= 1) m = fmaxf(m, __shfl_xor(m, dd));
    if (lane == 0) red[w] = m;
    __syncthreads();
    float gmax = red[r * 4];
#pragma unroll
    for (int k = 1; k < 4; k++) gmax = fmaxf(gmax, red[r * 4 + k]);
    const float cut = gmax - THR;
#pragma unroll
    for (int c = 0; c < 8; c++) {
        if (gg[c] > cut) {
            uint slot = atomicAdd(&cptr[r], 1u);
            if (slot < KCAP) {
                ejs[r][slot]  = (uint)(j0 + c);
                emks[r][slot] = mk[c];
                edgs[r][slot] = gg[c] - gmax;
            }
        }
    }
    __syncthreads();

    // ---- phase 2: gather; wave w = batch b; both rows ----
    const int b = w;
    const float* s2b = s2 + b * Nn;
    const float ab = ab_p[0];

#pragma unroll
    for (int rr = 0; rr < 2; rr++) {
        const int C = min(cptr[rr], (uint)KCAP);
        const float s1v = s1[b * Nn + i0 + rr] + ab;

        float4 acc = make_float4(0.f, 0.f, 0.f, 0.f);
        float psum = 0.f;

        uint  jA  = ejs[rr][0];
        float mkA = emks[rr][0];
        float dgA = edgs[rr][0];
        float s2A = s2b[jA];
        ushort4 hvA = *(const ushort4*)&h[((size_t)(b * Nn + jA)) * Ff + lane * 4];

        for (int c = 0; c < C; c++) {
            int cn = (c + 1 < C) ? c + 1 : c;
            uint  jB  = ejs[rr][cn];
            float mkB = emks[rr][cn];
            float dgB = edgs[rr][cn];
            float s2B = s2b[jB];
            ushort4 hvB = *(const ushort4*)&h[((size_t)(b * Nn + jB)) * Ff + lane * 4];
            float s = s1v + s2A;
            s = s > 0.f ? s : 0.1f * s;
            float p = __expf(s * mkA + dgA);
            psum += p;
            acc.x += p * bf2f(hvA.x);
            acc.y += p * bf2f(hvA.y);
            acc.z += p * bf2f(hvA.z);
            acc.w += p * bf2f(hvA.w);
            jA = jB; mkA = mkB; dgA = dgB; s2A = s2B; hvA = hvB;
        }

        float inv = 1.0f / psum;
        *(float4*)&out[((size_t)(b * Nn + i0 + rr)) * Ff + lane * 4] =
            make_float4(acc.x * inv, acc.y * inv, acc.z * inv, acc.w * inv);
    }
}

extern "C" void kernel_launch(void* const* d_in, const int* in_sizes, int n_in,
                              void* d_out, int out_size, void* d_ws, size_t ws_size,
                              hipStream_t stream) {
    const float* X    = (const float*)d_in[0];
    const float* Ageo = (const float*)d_in[1];
    const float* Dm   = (const float*)d_in[2];
    const float* Ww   = (const float*)d_in[3];
    const float* Wb   = (const float*)d_in[4];
    const float* a1   = (const float*)d_in[5];
    const float* a2   = (const float*)d_in[6];
    const float* ab   = (const float*)d_in[7];
    const float* thr  = (const float*)d_in[8];
    float* out = (float*)d_out;

    char* ws = (char*)d_ws;
    float* s1 = (float*)ws;                                        // B*N
    float* s2 = s1 + (size_t)Bsz * Nn;                             // B*N
    unsigned short* h = (unsigned short*)(s2 + (size_t)Bsz * Nn);  // B*N*F bf16 = 8 MB

    k_h<<<512, 256, 0, stream>>>(X, Ww, Wb, a1, a2, h, s1, s2);
    k_attn<<<Nn / 2, 512, 0, stream>>>(h, s1, s2, Ageo, Dm, ab, thr, out);
}

// Round 12
// 27.574 us; speedup vs baseline: 1.6198x; 1.6198x over previous
//
#include <hip/hip_runtime.h>
#include <hip/hip_bf16.h>
#include <math.h>

#define Bsz 8
#define Nn  2048
#define Ff  256
#define KCAP 1024
#define THR 60.0f

typedef short short8 __attribute__((ext_vector_type(8)));
typedef float f32x4  __attribute__((ext_vector_type(4)));
typedef unsigned short u16x4 __attribute__((ext_vector_type(4)));
typedef unsigned short u16x8 __attribute__((ext_vector_type(8)));
typedef unsigned int uint;

static __device__ __forceinline__ unsigned short f2bf(float v) {
    __hip_bfloat16 b = __float2bfloat16(v);
    return *reinterpret_cast<unsigned short*>(&b);
}
static __device__ __forceinline__ float bf2f(unsigned short u) {
    return __uint_as_float((uint)u << 16);
}
static __device__ __forceinline__ float fast_rcp(float x) {
    return __builtin_amdgcn_rcpf(x);
}

// ============ k_h: h = X@W^T + b -> h (B,N,F) bf16 row-major ; s1 ; s2 ============
// 256 blocks x 512 thr (8 waves); block = 64 n-rows, all 256 o.
// Software pipeline: chunk kc+1's W/X prefetched to REGISTERS during chunk kc's MFMAs.
__global__ __launch_bounds__(512) void k_h(const float* __restrict__ X,
                                           const float* __restrict__ W,
                                           const float* __restrict__ Wb,
                                           const float* __restrict__ a1,
                                           const float* __restrict__ a2,
                                           unsigned short* __restrict__ h,
                                           float* __restrict__ s1,
                                           float* __restrict__ s2) {
    __shared__ char smem[45056];
    char* w_lds = smem;                                 // [256 o][64 f] bf16, byte ^= (o&7)<<4 ; reused as h-tile
    char* x_lds = smem + 32768;                         // [64 n][64 f] bf16, byte ^= (n&7)<<4
    float (*sred1)[4][16] = (float(*)[4][16])(smem + 40960);          // [8][4][16]
    float (*sred2)[4][16] = (float(*)[4][16])(smem + 40960 + 2048);   // [8][4][16]

    const int tid  = threadIdx.x;
    const int lane = tid & 63;
    const int w    = tid >> 6;          // 0..7, o-slice w*32..w*32+31
    const int r0   = blockIdx.x * 64;
    const int b    = r0 >> 11;
    const int n0   = r0 & 2047;

    f32x4 acc[2][4];
#pragma unroll
    for (int mt = 0; mt < 2; mt++)
#pragma unroll
        for (int nt = 0; nt < 4; nt++) acc[mt][nt] = (f32x4)0.f;

    float4 wv[8], xv[2];
    auto gload = [&](int kc) {
        const int f0 = kc * 64;
#pragma unroll
        for (int p = 0; p < 8; p++) {
            int idx = tid + p * 512;
            int o = idx >> 4, fi = idx & 15;
            wv[p] = *(const float4*)&W[(size_t)o * Ff + f0 + fi * 4];
        }
#pragma unroll
        for (int p = 0; p < 2; p++) {
            int idx = tid + p * 512;
            int n = idx >> 4, fi = idx & 15;
            xv[p] = *(const float4*)&X[(size_t)(r0 + n) * Ff + f0 + fi * 4];
        }
    };
    auto swrite = [&]() {
#pragma unroll
        for (int p = 0; p < 8; p++) {
            int idx = tid + p * 512;
            int o = idx >> 4, fi = idx & 15;
            u16x4 pk = {f2bf(wv[p].x), f2bf(wv[p].y), f2bf(wv[p].z), f2bf(wv[p].w)};
            *(u16x4*)(w_lds + ((o * 128 + fi * 8) ^ ((o & 7) << 4))) = pk;
        }
#pragma unroll
        for (int p = 0; p < 2; p++) {
            int idx = tid + p * 512;
            int n = idx >> 4, fi = idx & 15;
            u16x4 pk = {f2bf(xv[p].x), f2bf(xv[p].y), f2bf(xv[p].z), f2bf(xv[p].w)};
            *(u16x4*)(x_lds + ((n * 128 + fi * 8) ^ ((n & 7) << 4))) = pk;
        }
    };

    gload(0);
    for (int kc = 0; kc < 4; kc++) {
        __syncthreads();          // previous chunk's MFMA reads done; LDS free
        swrite();
        __syncthreads();          // chunk staged
        if (kc < 3) gload(kc + 1);    // in flight during MFMA below
#pragma unroll
        for (int kt = 0; kt < 2; kt++) {
            short8 bfr[4];
#pragma unroll
            for (int nt = 0; nt < 4; nt++) {
                int n = nt * 16 + (lane & 15);
                bfr[nt] = *(const short8*)(x_lds + ((n * 128 + kt * 64 + (lane >> 4) * 16) ^ ((n & 7) << 4)));
            }
#pragma unroll
            for (int mt = 0; mt < 2; mt++) {
                int o = w * 32 + mt * 16 + (lane & 15);
                short8 afr = *(const short8*)(w_lds + ((o * 128 + kt * 64 + (lane >> 4) * 16) ^ ((o & 7) << 4)));
#pragma unroll
                for (int nt = 0; nt < 4; nt++)
                    acc[mt][nt] = __builtin_amdgcn_mfma_f32_16x16x32_bf16(afr, bfr[nt], acc[mt][nt], 0, 0, 0);
            }
        }
    }

    // epilogue: bias, s1/s2 partials, h tile -> LDS (row-major, swizzled)
    __syncthreads();    // MFMA reads done; reuse w_lds as h tile [64 n][256 o] bf16
    float s1p[4] = {0.f, 0.f, 0.f, 0.f};
    float s2p[4] = {0.f, 0.f, 0.f, 0.f};
#pragma unroll
    for (int mt = 0; mt < 2; mt++) {
#pragma unroll
        for (int reg = 0; reg < 4; reg++) {
            int o = w * 32 + mt * 16 + (lane >> 4) * 4 + reg;
            float wb = Wb[o], a1v = a1[o], a2v = a2[o];
#pragma unroll
            for (int nt = 0; nt < 4; nt++) {
                float hv = acc[mt][nt][reg] + wb;
                int nl = nt * 16 + (lane & 15);
                *(unsigned short*)(w_lds + nl * 512 + ((o * 2) ^ ((nl & 7) << 4))) = f2bf(hv);
                s1p[nt] += hv * a1v;
                s2p[nt] += hv * a2v;
            }
        }
    }
#pragma unroll
    for (int nt = 0; nt < 4; nt++) {
        s1p[nt] += __shfl_xor(s1p[nt], 16); s1p[nt] += __shfl_xor(s1p[nt], 32);
        s2p[nt] += __shfl_xor(s2p[nt], 16); s2p[nt] += __shfl_xor(s2p[nt], 32);
    }
    if (lane < 16) {
#pragma unroll
        for (int nt = 0; nt < 4; nt++) { sred1[w][nt][lane] = s1p[nt]; sred2[w][nt][lane] = s2p[nt]; }
    }
    __syncthreads();

    // coalesced h store: 64 rows x 256 cols bf16 = 32 KB, 512 thr x 16B x 4 iters
#pragma unroll
    for (int p = 0; p < 4; p++) {
        int id = tid + p * 512;
        int nl = id >> 5;
        int c16 = (id & 31) * 16;
        u16x8 v = *(const u16x8*)(w_lds + nl * 512 + (c16 ^ ((nl & 7) << 4)));
        *(u16x8*)&h[((size_t)(b * Nn + n0 + nl)) * Ff + (id & 31) * 8] = v;
    }
    if (tid < 64) {
        int nt = tid >> 4, col = tid & 15;
        float v = 0.f;
#pragma unroll
        for (int k = 0; k < 8; k++) v += sred1[k][nt][col];
        s1[b * Nn + n0 + nt * 16 + col] = v;
    } else if (tid < 128) {
        int t2 = tid - 64;
        int nt = t2 >> 4, col = t2 & 15;
        float v = 0.f;
#pragma unroll
        for (int k = 0; k < 8; k++) v += sred2[k][nt][col];
        s2[b * Nn + n0 + nt * 16 + col] = v;
    }
}

// ============ k_attn: fused shortlist + sparse gather-softmax (R10 form) ============
// grid = N blocks x 512 thr; block = row i.
// phase 1: build shortlist {j, mk, g-gmax} for all j with g > gmax - THR (in LDS).
// phase 2: wave w = batch b; lane owns 4 f-cols; gather h rows over shortlist.
__global__ __launch_bounds__(512) void k_attn(const unsigned short* __restrict__ h,
                                              const float* __restrict__ s1,
                                              const float* __restrict__ s2,
                                              const float* __restrict__ Ageo,
                                              const float* __restrict__ Dm,
                                              const float* __restrict__ ab_p,
                                              const float* __restrict__ thr_p,
                                              float* __restrict__ out) {
    __shared__ uint  ejs[KCAP];
    __shared__ float emks[KCAP];
    __shared__ float edgs[KCAP];
    __shared__ float red[8];
    __shared__ uint  cptr;

    const int i    = blockIdx.x;
    const int tid  = threadIdx.x;
    const int lane = tid & 63;
    const int w    = tid >> 6;      // wave = batch
    const float c10 = 10.0f * thr_p[0];

    // ---- phase 1: shortlist for row i ----
    if (tid == 0) cptr = 0;
    const int j0 = tid * 4;
    float4 a = *(const float4*)&Ageo[(size_t)i * Nn + j0];
    float4 d = *(const float4*)&Dm[(size_t)i * Nn + j0];
    float av[4] = {a.x, a.y, a.z, a.w};
    float dv[4] = {d.x, d.y, d.z, d.w};
    float mk[4], gg[4];
    float m = 0.0f;
#pragma unroll
    for (int c = 0; c < 4; c++) {
        float dd = (j0 + c == i) ? 1.0f : dv[c];
        float mkv = fast_rcp(1.0f + __expf(c10 - 10.0f * av[c]));
        float g   = mkv * fast_rcp(dd + 1e-5f);
        mk[c] = mkv;
        gg[c] = g;
        m = fmaxf(m, g);
    }
#pragma unroll
    for (int dd = 32; dd; dd >>= 1) m = fmaxf(m, __shfl_xor(m, dd));
    if (lane == 0) red[w] = m;
    __syncthreads();
    float gmax = red[0];
#pragma unroll
    for (int k = 1; k < 8; k++) gmax = fmaxf(gmax, red[k]);
    const float cut = gmax - THR;
#pragma unroll
    for (int c = 0; c < 4; c++) {
        if (gg[c] > cut) {
            uint slot = atomicAdd(&cptr, 1u);
            if (slot < KCAP) {
                ejs[slot]  = (uint)(j0 + c);
                emks[slot] = mk[c];
                edgs[slot] = gg[c] - gmax;
            }
        }
    }
    __syncthreads();
    const int C = min(cptr, (uint)KCAP);

    // ---- phase 2: gather over shortlist; wave w = batch b ----
    const int b = w;
    const float s1v = s1[b * Nn + i] + ab_p[0];
    const float* s2b = s2 + b * Nn;

    float4 acc = make_float4(0.f, 0.f, 0.f, 0.f);
    float psum = 0.f;

    uint  jA  = ejs[0];
    float mkA = emks[0];
    float dgA = edgs[0];
    float s2A = s2b[jA];
    ushort4 hvA = *(const ushort4*)&h[((size_t)(b * Nn + jA)) * Ff + lane * 4];

    for (int c = 0; c < C; c++) {
        int cn = (c + 1 < C) ? c + 1 : c;
        uint  jB  = ejs[cn];
        float mkB = emks[cn];
        float dgB = edgs[cn];
        float s2B = s2b[jB];
        ushort4 hvB = *(const ushort4*)&h[((size_t)(b * Nn + jB)) * Ff + lane * 4];
        float s = s1v + s2A;
        s = s > 0.f ? s : 0.1f * s;
        float p = __expf(s * mkA + dgA);
        psum += p;
        acc.x += p * bf2f(hvA.x);
        acc.y += p * bf2f(hvA.y);
        acc.z += p * bf2f(hvA.z);
        acc.w += p * bf2f(hvA.w);
        jA = jB; mkA = mkB; dgA = dgB; s2A = s2B; hvA = hvB;
    }

    float inv = 1.0f / psum;
    *(float4*)&out[((size_t)(b * Nn + i)) * Ff + lane * 4] =
        make_float4(acc.x * inv, acc.y * inv, acc.z * inv, acc.w * inv);
}

extern "C" void kernel_launch(void* const* d_in, const int* in_sizes, int n_in,
                              void* d_out, int out_size, void* d_ws, size_t ws_size,
                              hipStream_t stream) {
    const float* X    = (const float*)d_in[0];
    const float* Ageo = (const float*)d_in[1];
    const float* Dm   = (const float*)d_in[2];
    const float* Ww   = (const float*)d_in[3];
    const float* Wb   = (const float*)d_in[4];
    const float* a1   = (const float*)d_in[5];
    const float* a2   = (const float*)d_in[6];
    const float* ab   = (const float*)d_in[7];
    const float* thr  = (const float*)d_in[8];
    float* out = (float*)d_out;

    char* ws = (char*)d_ws;
    float* s1 = (float*)ws;                                        // B*N
    float* s2 = s1 + (size_t)Bsz * Nn;                             // B*N
    unsigned short* h = (unsigned short*)(s2 + (size_t)Bsz * Nn);  // B*N*F bf16 = 8 MB

    k_h<<<256, 512, 0, stream>>>(X, Ww, Wb, a1, a2, h, s1, s2);
    k_attn<<<Nn, 512, 0, stream>>>(h, s1, s2, Ageo, Dm, ab, thr, out);
}